// Round 4
// baseline (275.744 us; speedup 1.0000x reference)
//
#include <hip/hip_runtime.h>
#include <math.h>

// Problem: B=16 rows, D=2^21 fp32 per row.
// loss = mean_i( sqrt( sum_j (out[i,j]-lab[i,j])^2 ) )
//
// R5 == R4 resubmitted (R4 died to a container failure with no counters; the
// kernel audits clean for hang/fault risks, so the experiment is re-run).
// Background: rounds 2-3 proved hipcc re-serializes ANY source-level load
// batching (VGPR stuck at 24-32; loads sunk at ISel, MLP~2, vmcnt(0) each
// pair, 2.68 TB/s effective, VALUBusy 2.5%). This version takes manual
// control: inline-asm global_load_dwordx4 (issue order = program order,
// un-sinkable), counted s_waitcnt vmcnt(6) (never 0 until the drain tail),
// sched_barrier(0) after each wait (rule #18: register-only VALU otherwise
// hoists past an asm waitcnt). 8 loads (8 KB) in flight per wave steady-state.

constexpr int B = 16;
constexpr int D = 2097152;                         // 2^21 floats per row
constexpr int THREADS = 256;                       // 4 waves per block
constexpr int BLOCKS_PER_ROW = 128;
constexpr int GRID = B * BLOCKS_PER_ROW;           // 2048 blocks
constexpr int F4_PER_ROW = D / 4;                  // 524288
constexpr int F4_PER_BLOCK = F4_PER_ROW / BLOCKS_PER_ROW;   // 4096

using f32x4 = __attribute__((ext_vector_type(4))) float;

__device__ __forceinline__ f32x4 gload(const f32x4* p) {
    f32x4 r;
    // Early-clobber: dest tuple must not alias the address pair.
    asm volatile("global_load_dwordx4 %0, %1, off" : "=&v"(r) : "v"(p) : "memory");
    return r;
}

#define WAIT_VMCNT(n) asm volatile("s_waitcnt vmcnt(" #n ")" ::: "memory")
#define SB() __builtin_amdgcn_sched_barrier(0)

__global__ __launch_bounds__(THREADS, 4)           // VGPR cap 128: room for pipeline
void sqdiff_partial_kernel(const float4* __restrict__ out,
                           const float4* __restrict__ lab,
                           float* __restrict__ partials) {
    const int row   = blockIdx.x >> 7;             // / BLOCKS_PER_ROW
    const int chunk = blockIdx.x & (BLOCKS_PER_ROW - 1);
    const size_t base = (size_t)row * F4_PER_ROW
                      + (size_t)chunk * F4_PER_BLOCK
                      + (size_t)threadIdx.x;

    const f32x4* op = reinterpret_cast<const f32x4*>(out) + base;
    const f32x4* lp = reinterpret_cast<const f32x4*>(lab) + base;

    // 4-slot rotating register file; all indices are literals.
    f32x4 ob[4], lb[4];
    float a0 = 0.0f, a1 = 0.0f, a2 = 0.0f, a3 = 0.0f;

#define ISSUE(k) do { \
        ob[(k) & 3] = gload(op + (size_t)(k) * THREADS); \
        lb[(k) & 3] = gload(lp + (size_t)(k) * THREADS); } while (0)

#define COMPUTE(k) do { \
        const f32x4 o = ob[(k) & 3]; \
        const f32x4 l = lb[(k) & 3]; \
        const float dx = o[0] - l[0]; \
        const float dy = o[1] - l[1]; \
        const float dz = o[2] - l[2]; \
        const float dw = o[3] - l[3]; \
        a0 = fmaf(dx, dx, a0); \
        a1 = fmaf(dy, dy, a1); \
        a2 = fmaf(dz, dz, a2); \
        a3 = fmaf(dw, dw, a3); } while (0)

    // Prologue: pairs 0..2 in flight (6 loads).
    ISSUE(0); ISSUE(1); ISSUE(2);

    // Steady state: issue pair k+3, wait vmcnt(6) (=> pair k complete,
    // 6 loads still in flight), compute pair k.
    ISSUE(3);  WAIT_VMCNT(6); SB(); COMPUTE(0);
    ISSUE(4);  WAIT_VMCNT(6); SB(); COMPUTE(1);
    ISSUE(5);  WAIT_VMCNT(6); SB(); COMPUTE(2);
    ISSUE(6);  WAIT_VMCNT(6); SB(); COMPUTE(3);
    ISSUE(7);  WAIT_VMCNT(6); SB(); COMPUTE(4);
    ISSUE(8);  WAIT_VMCNT(6); SB(); COMPUTE(5);
    ISSUE(9);  WAIT_VMCNT(6); SB(); COMPUTE(6);
    ISSUE(10); WAIT_VMCNT(6); SB(); COMPUTE(7);
    ISSUE(11); WAIT_VMCNT(6); SB(); COMPUTE(8);
    ISSUE(12); WAIT_VMCNT(6); SB(); COMPUTE(9);
    ISSUE(13); WAIT_VMCNT(6); SB(); COMPUTE(10);
    ISSUE(14); WAIT_VMCNT(6); SB(); COMPUTE(11);
    ISSUE(15); WAIT_VMCNT(6); SB(); COMPUTE(12);
    // Drain tail.
    WAIT_VMCNT(4); SB(); COMPUTE(13);
    WAIT_VMCNT(2); SB(); COMPUTE(14);
    WAIT_VMCNT(0); SB(); COMPUTE(15);

#undef ISSUE
#undef COMPUTE

    float acc = (a0 + a1) + (a2 + a3);

    // wave-64 tree reduce
#pragma unroll
    for (int off = 32; off > 0; off >>= 1)
        acc += __shfl_down(acc, off, 64);

    __shared__ float smem[THREADS / 64];
    const int lane = threadIdx.x & 63;
    const int wave = threadIdx.x >> 6;
    if (lane == 0) smem[wave] = acc;
    __syncthreads();

    if (threadIdx.x == 0) {
        // plain store, no atomic: partials laid out [row][chunk] == blockIdx.x
        partials[blockIdx.x] = smem[0] + smem[1] + smem[2] + smem[3];
    }
}

// One block, 1024 threads = 16 waves. Wave w reduces row w's 128 partials.
__global__ __launch_bounds__(1024)
void finalize_kernel(const float* __restrict__ partials,
                     float* __restrict__ loss) {
    const int wave = threadIdx.x >> 6;   // 0..15 == row
    const int lane = threadIdx.x & 63;

    float s = partials[wave * BLOCKS_PER_ROW + lane]
            + partials[wave * BLOCKS_PER_ROW + 64 + lane];

#pragma unroll
    for (int off = 32; off > 0; off >>= 1)
        s += __shfl_down(s, off, 64);

    __shared__ float row_dist[B];
    if (lane == 0) row_dist[wave] = sqrtf(s);
    __syncthreads();

    if (wave == 0) {
        float v = (lane < B) ? row_dist[lane] : 0.0f;
#pragma unroll
        for (int off = 32; off > 0; off >>= 1)
            v += __shfl_down(v, off, 64);
        if (lane == 0) loss[0] = v * (1.0f / (float)B);
    }
}

extern "C" void kernel_launch(void* const* d_in, const int* in_sizes, int n_in,
                              void* d_out, int out_size, void* d_ws, size_t ws_size,
                              hipStream_t stream) {
    const float4* out_p = (const float4*)d_in[0];
    const float4* lab_p = (const float4*)d_in[1];
    float* partials = (float*)d_ws;      // 2048 floats of scratch, fully overwritten

    sqdiff_partial_kernel<<<GRID, THREADS, 0, stream>>>(out_p, lab_p, partials);
    finalize_kernel<<<1, 1024, 0, stream>>>(partials, (float*)d_out);
}

// Round 6
// 246.782 us; speedup vs baseline: 1.1174x; 1.1174x over previous
//
#include <hip/hip_runtime.h>
#include <math.h>

// Problem: B=16 rows, D=2^21 fp32 per row.
// loss = mean_i( sqrt( sum_j (out[i,j]-lab[i,j])^2 ) )
//
// R7 == R6 with the compile error fixed (__builtin_nontemporal_load requires
// a vector-of-scalar type; HIP's float4 is a struct -> use ext_vector_type).
//
// Theory (from R2-R5 evidence): duration ~100us / 2.68 TB/s effective is
// INVARIANT to wave-level ILP (compiler MLP~2 == forced asm pipeline MLP~8).
// Queueing math: 6.3us per load-pair vs ~0.4us bare latency => memory system
// saturated; queueing dominates. Saturated tier is not HBM (21%) nor L2 (8%).
// Prime suspect: Infinity Cache churn - 268 MB one-touch stream vs 256 MB L3,
// FETCH_SIZE = exactly 50% of working set every round (miss-evict-fill on
// every line). Streaming gets zero reuse from L3 -> bypass it with nt loads.
// Decisive either way: right -> all 268 MB from HBM at ~5-6 TB/s, partial
// kernel ~45-55us. Wrong -> ~200us, limit is downstream of L3 = roofline.

constexpr int B = 16;
constexpr int D = 2097152;                         // 2^21 floats per row
constexpr int THREADS = 256;                       // 4 waves per block
constexpr int BLOCKS_PER_ROW = 128;
constexpr int GRID = B * BLOCKS_PER_ROW;           // 2048 = 256 CUs * 8 blocks
constexpr int F4_PER_ROW = D / 4;                  // 524288
constexpr int F4_PER_BLOCK = F4_PER_ROW / BLOCKS_PER_ROW;   // 4096
constexpr int BATCH = 4;                           // float4 per stream per batch
constexpr int F4_PER_BATCH = THREADS * BATCH;      // 1024
constexpr int NBATCH = F4_PER_BLOCK / F4_PER_BATCH;         // 4

using f32x4 = __attribute__((ext_vector_type(4))) float;

__global__ __launch_bounds__(THREADS, 8)
void sqdiff_partial_kernel(const float4* __restrict__ out,
                           const float4* __restrict__ lab,
                           float* __restrict__ partials) {
    const int row   = blockIdx.x >> 7;             // / BLOCKS_PER_ROW
    const int chunk = blockIdx.x & (BLOCKS_PER_ROW - 1);
    const size_t blockbase = (size_t)row * F4_PER_ROW
                           + (size_t)chunk * F4_PER_BLOCK;

    const f32x4* op = reinterpret_cast<const f32x4*>(out);
    const f32x4* lp = reinterpret_cast<const f32x4*>(lab);

    float a0 = 0.0f, a1 = 0.0f, a2 = 0.0f, a3 = 0.0f;

#pragma unroll 1
    for (int b = 0; b < NBATCH; ++b) {
        const size_t idx = blockbase + (size_t)b * F4_PER_BATCH + threadIdx.x;

        f32x4 o[BATCH], l[BATCH];
#pragma unroll
        for (int i = 0; i < BATCH; ++i)
            o[i] = __builtin_nontemporal_load(op + idx + (size_t)i * THREADS);
#pragma unroll
        for (int i = 0; i < BATCH; ++i)
            l[i] = __builtin_nontemporal_load(lp + idx + (size_t)i * THREADS);

#pragma unroll
        for (int i = 0; i < BATCH; ++i) {
            const float dx = o[i][0] - l[i][0];
            const float dy = o[i][1] - l[i][1];
            const float dz = o[i][2] - l[i][2];
            const float dw = o[i][3] - l[i][3];
            a0 = fmaf(dx, dx, a0);                 // 4 independent chains
            a1 = fmaf(dy, dy, a1);
            a2 = fmaf(dz, dz, a2);
            a3 = fmaf(dw, dw, a3);
        }
    }

    float acc = (a0 + a1) + (a2 + a3);

    // wave-64 tree reduce
#pragma unroll
    for (int off = 32; off > 0; off >>= 1)
        acc += __shfl_down(acc, off, 64);

    __shared__ float smem[THREADS / 64];
    const int lane = threadIdx.x & 63;
    const int wave = threadIdx.x >> 6;
    if (lane == 0) smem[wave] = acc;
    __syncthreads();

    if (threadIdx.x == 0) {
        // plain store, no atomic: partials laid out [row][chunk] == blockIdx.x
        partials[blockIdx.x] = smem[0] + smem[1] + smem[2] + smem[3];
    }
}

// One block, 1024 threads = 16 waves. Wave w reduces row w's 128 partials.
__global__ __launch_bounds__(1024)
void finalize_kernel(const float* __restrict__ partials,
                     float* __restrict__ loss) {
    const int wave = threadIdx.x >> 6;   // 0..15 == row
    const int lane = threadIdx.x & 63;

    float s = partials[wave * BLOCKS_PER_ROW + lane]
            + partials[wave * BLOCKS_PER_ROW + 64 + lane];

#pragma unroll
    for (int off = 32; off > 0; off >>= 1)
        s += __shfl_down(s, off, 64);

    __shared__ float row_dist[B];
    if (lane == 0) row_dist[wave] = sqrtf(s);
    __syncthreads();

    if (wave == 0) {
        float v = (lane < B) ? row_dist[lane] : 0.0f;
#pragma unroll
        for (int off = 32; off > 0; off >>= 1)
            v += __shfl_down(v, off, 64);
        if (lane == 0) loss[0] = v * (1.0f / (float)B);
    }
}

extern "C" void kernel_launch(void* const* d_in, const int* in_sizes, int n_in,
                              void* d_out, int out_size, void* d_ws, size_t ws_size,
                              hipStream_t stream) {
    const float4* out_p = (const float4*)d_in[0];
    const float4* lab_p = (const float4*)d_in[1];
    float* partials = (float*)d_ws;      // 2048 floats of scratch, fully overwritten

    sqdiff_partial_kernel<<<GRID, THREADS, 0, stream>>>(out_p, lab_p, partials);
    finalize_kernel<<<1, 1024, 0, stream>>>(partials, (float*)d_out);
}